// Round 2
// baseline (80.706 us; speedup 1.0000x reference)
//
#include <hip/hip_runtime.h>

// Bernstein->monomial basis change, degree 5, with input remap t=(x+1)/2 folded in:
// B_i((x+1)/2) = sum_d Mb[i][d] * x^d   (entries exact in fp32: integer/32)
__device__ __constant__ float Mb[6][6] = {
    { 0.03125f, -0.15625f,  0.3125f, -0.3125f,  0.15625f, -0.03125f},
    { 0.15625f, -0.46875f,  0.3125f,  0.3125f, -0.46875f,  0.15625f},
    { 0.3125f,  -0.3125f,  -0.625f,   0.625f,   0.3125f,  -0.3125f },
    { 0.3125f,   0.3125f,  -0.625f,  -0.625f,   0.3125f,   0.3125f },
    { 0.15625f,  0.46875f,  0.3125f, -0.3125f, -0.46875f, -0.15625f},
    { 0.03125f,  0.15625f,  0.3125f,  0.3125f,  0.15625f,  0.03125f},
};

// Kernel 1 (one block): p[3][6][6][6] (Bernstein) -> monomial coeffs
// A[c][i][j][k] in d_ws, with q' = 2q-1 folded in. ~12k FMAs, ~2-3 us.
__global__ __launch_bounds__(256) void ffd_coeffs(const float* __restrict__ p,
                                                  float* __restrict__ A)
{
    __shared__ float b0[648];
    __shared__ float b1[648];
    const int t = threadIdx.x;

    for (int m = t; m < 648; m += 256) b0[m] = p[m];
    __syncthreads();

    // k -> dk  (b0 -> b1)
    for (int m = t; m < 648; m += 256) {
        const int dk = m % 6;
        const int base = (m / 6) * 6;
        float s = 0.f;
        #pragma unroll
        for (int k = 0; k < 6; ++k) s = fmaf(b0[base + k], Mb[k][dk], s);
        b1[m] = s;
    }
    __syncthreads();

    // j -> dj  (b1 -> b0)
    for (int m = t; m < 648; m += 256) {
        const int dk = m % 6;
        const int dj = (m / 6) % 6;
        const int ci = m / 36;               // ci = c*6 + i
        float s = 0.f;
        #pragma unroll
        for (int j = 0; j < 6; ++j) s = fmaf(b1[(ci * 6 + j) * 6 + dk], Mb[j][dj], s);
        b0[m] = s;
    }
    __syncthreads();

    // i -> di, fold in q' = 2q - 1, write straight to global A.
    for (int m = t; m < 648; m += 256) {
        const int dk = m % 6;
        const int dj = (m / 6) % 6;
        const int di = (m / 36) % 6;
        const int c  = m / 216;
        float s = 0.f;
        #pragma unroll
        for (int i = 0; i < 6; ++i) s = fmaf(b0[((c * 6 + i) * 6 + dj) * 6 + dk], Mb[i][di], s);
        s *= 2.0f;
        if (di == 0 && dj == 0 && dk == 0) s -= 1.0f;
        A[m] = s;
    }
}

// Kernel 2: evaluation, 2 vertices/thread, no LDS, no barriers.
// Coefficients are read per (c,i) block (36 floats) through a wave-uniform
// (readfirstlane-forced) address -> scalar K$ loads into SGPRs; v_fma_f32
// consumes one SGPR operand directly, so the Horner chains run at VALU issue
// rate. Low VGPR count -> near-full occupancy; fully static indexing
// everywhere (c-loop unrolled) so nothing spills to scratch.
__global__ __launch_bounds__(256) void ffd_eval(const float* __restrict__ verts,
                                                const float* __restrict__ A,
                                                float* __restrict__ out, int N)
{
    const long long v0 = ((long long)blockIdx.x * 256 + threadIdx.x) * 2;
    if (v0 >= N) return;

    float x[2], y[2], z[2];
    const bool full = (v0 + 2 <= N);
    if (full) {
        const float2* vp = (const float2*)(verts + v0 * 3);  // 24B stride -> 8B aligned
        const float2 f0 = vp[0], f1 = vp[1], f2 = vp[2];
        x[0] = f0.x; y[0] = f0.y; z[0] = f1.x;
        x[1] = f1.y; y[1] = f2.x; z[1] = f2.y;
    } else {
        for (int v = 0; v < 2; ++v) {
            long long n = v0 + v; if (n >= N) n = N - 1;
            x[v] = verts[n * 3 + 0]; y[v] = verts[n * 3 + 1]; z[v] = verts[n * 3 + 2];
        }
    }

    float res[6];
    #pragma unroll
    for (int c = 0; c < 3; ++c) {
        float q0 = 0.f, q1 = 0.f;
        #pragma unroll 1
        for (int ii = 0; ii < 6; ++ii) {
            const int i = 5 - ii;
            // Wave-uniform offset -> scalar loads (36 dwords = s_load x16/x16/x4).
            const int off = __builtin_amdgcn_readfirstlane((c * 6 + i) * 36);
            const float* __restrict__ Ab = A + off;
            float a[36];
            #pragma unroll
            for (int r = 0; r < 36; ++r) a[r] = Ab[r];

            float t0 = 0.f, t1 = 0.f;
            #pragma unroll
            for (int jj = 0; jj < 6; ++jj) {
                const int j = 5 - jj;
                const float* Ak = a + j * 6;
                float s0 = fmaf(Ak[5], z[0], Ak[4]);
                s0 = fmaf(s0, z[0], Ak[3]);
                s0 = fmaf(s0, z[0], Ak[2]);
                s0 = fmaf(s0, z[0], Ak[1]);
                s0 = fmaf(s0, z[0], Ak[0]);
                float s1 = fmaf(Ak[5], z[1], Ak[4]);
                s1 = fmaf(s1, z[1], Ak[3]);
                s1 = fmaf(s1, z[1], Ak[2]);
                s1 = fmaf(s1, z[1], Ak[1]);
                s1 = fmaf(s1, z[1], Ak[0]);
                t0 = (jj == 0) ? s0 : fmaf(t0, y[0], s0);
                t1 = (jj == 0) ? s1 : fmaf(t1, y[1], s1);
            }
            q0 = (ii == 0) ? t0 : fmaf(q0, x[0], t0);
            q1 = (ii == 0) ? t1 : fmaf(q1, x[1], t1);
        }
        res[c]     = q0;   // static indices -> registers, no scratch
        res[3 + c] = q1;
    }

    if (full) {
        float2* op = (float2*)(out + v0 * 3);
        op[0] = make_float2(res[0], res[1]);
        op[1] = make_float2(res[2], res[3]);
        op[2] = make_float2(res[4], res[5]);
    } else {
        for (int v = 0; v < 2; ++v) {
            const long long n = v0 + v;
            if (n < N) {
                out[n * 3 + 0] = res[v * 3 + 0];
                out[n * 3 + 1] = res[v * 3 + 1];
                out[n * 3 + 2] = res[v * 3 + 2];
            }
        }
    }
}

extern "C" void kernel_launch(void* const* d_in, const int* in_sizes, int n_in,
                              void* d_out, int out_size, void* d_ws, size_t ws_size,
                              hipStream_t stream)
{
    const float* verts = (const float*)d_in[0];   // [N,3] fp32
    const float* p     = (const float*)d_in[1];   // [3,6,6,6] fp32
    float* out = (float*)d_out;                   // [1,N,3] fp32
    float* A   = (float*)d_ws;                    // 648 floats of workspace
    const int N = in_sizes[0] / 3;

    ffd_coeffs<<<1, 256, 0, stream>>>(p, A);

    const int nthreads = (N + 1) / 2;
    const int blocks = (nthreads + 255) / 256;
    ffd_eval<<<blocks, 256, 0, stream>>>(verts, A, out, N);
}